// Round 8
// baseline (526.325 us; speedup 1.0000x reference)
//
#include <hip/hip_runtime.h>

#define NB 8
#define NC 256
#define DF 16384
#define KCL 16
#define SPLITS 8
#define KC (DF / SPLITS)     // 2048
#define BK 32
#define ITERS (KC / BK)      // 64
#define NPAIR 10             // 64x64 upper-tri pairs
#define GEMM_BLOCKS (NPAIR * NB * SPLITS)   // 640

typedef _Float16 half8 __attribute__((ext_vector_type(8)));
typedef float floatx4 __attribute__((ext_vector_type(4)));

__device__ const int TItab[NPAIR] = {0,0,0,0,1,1,1,2,2,3};
__device__ const int TJtab[NPAIR] = {0,1,2,3,1,2,3,2,3,3};

__device__ __forceinline__ void signal(int* p) {
  __hip_atomic_fetch_add(p, 1, __ATOMIC_RELEASE, __HIP_MEMORY_SCOPE_AGENT);
}
__device__ __forceinline__ void waitfor(int* p, int target) {
  while (__hip_atomic_load(p, __ATOMIC_ACQUIRE, __HIP_MEMORY_SCOPE_AGENT) < target)
    __builtin_amdgcn_s_sleep(8);
}

// ---------------- argmax over 256 threads (first occurrence) ---------------------
__device__ __forceinline__ int argmax256(float v, float* sv, int* si) {
  int t = threadIdx.x;
  sv[t] = v; si[t] = t;
  __syncthreads();
  #pragma unroll
  for (int s = 128; s >= 1; s >>= 1) {
    if (t < s) {
      float a = sv[t], b = sv[t + s];
      int ia = si[t], ib = si[t + s];
      if (b > a || (b == a && ib < ia)) { sv[t] = b; si[t] = ib; }
    }
    __syncthreads();
  }
  int r = si[0];
  __syncthreads();
  return r;
}

// =====================================================================
// ONE kernel: [gemm 640 blocks | pos-FPS block 640] -> formD (blocks 0..255)
// -> FPS (blocks 0,32,..,224) -> final (block 0), chained by atomic flags.
// All 641 blocks co-resident: 3 blocks/CU * 256 CU = 768 >= 641.
// =====================================================================
__global__ __launch_bounds__(256, 3) void k_fused(const float* __restrict__ ff,
                                                  const float* __restrict__ pe,
                                                  float* __restrict__ Pp,
                                                  float* __restrict__ Db,
                                                  float* __restrict__ rsp,
                                                  float* __restrict__ centers0,
                                                  float* __restrict__ ccoord,
                                                  int* __restrict__ cnts,
                                                  int* __restrict__ outp) {
  // counters: gdone[8]=cnts+0, fcnt[8]=cnts+8, fpsdone=cnts+16, predone=cnts+17
  __shared__ _Float16 Ah[64][40];   // pad 32->40: frag reads 2-way bank alias (free)
  __shared__ _Float16 Al[64][40];
  __shared__ _Float16 Bh[64][40];
  __shared__ _Float16 Bl[64][40];
  __shared__ float sv[NC]; __shared__ int si[NC];
  __shared__ int fpsIdx[KCL];
  __shared__ float dg_s[NC];

  const int bid = blockIdx.x;
  const int t = threadIdx.x;

  if (bid == GEMM_BLOCKS) {
    // ---- pos-FPS (256 threads), LDS aliased onto gemm tiles ----
    float* px = (float*)&Ah[0][0];
    float* py = px + 256;
    float* pz = px + 512;
    float* pn = px + 768;
    float x = pe[t * 3 + 0], y = pe[t * 3 + 1], z = pe[t * 3 + 2];
    px[t] = x; py[t] = y; pz[t] = z;
    float n = x * x + y * y + z * z;
    pn[t] = n;
    __syncthreads();
    float rsum = 0.f;
    for (int j = 0; j < NC; ++j) {
      float dot = x * px[j] + y * py[j] + z * pz[j];
      rsum += sqrtf(fmaxf(n + pn[j] - 2.f * dot, 0.f));
    }
    int start = argmax256(rsum, sv, si);
    if (t == 0) fpsIdx[0] = start;
    float dot0 = x * px[start] + y * py[start] + z * pz[start];
    float mind = sqrtf(fmaxf(n + pn[start] - 2.f * dot0, 0.f));
    for (int it = 1; it < KCL; ++it) {
      int far = argmax256(mind, sv, si);
      if (t == 0) fpsIdx[it] = far;
      float dot = x * px[far] + y * py[far] + z * pz[far];
      mind = fminf(mind, sqrtf(fmaxf(n + pn[far] - 2.f * dot, 0.f)));
    }
    __syncthreads();
    if (t < KCL) {
      int p = fpsIdx[t];
      centers0[t * 3 + 0] = px[p];
      centers0[t * 3 + 1] = py[p];
      centers0[t * 3 + 2] = pz[p];
    }
    __threadfence();
    __syncthreads();
    if (t == 0) signal(&cnts[17]);
    return;
  }

  // ================= gemm phase (R3 config: 64x64 tiles, 3 chains) ==============
  {
    const int tp = bid % 10;
    const int b  = (bid / 10) & 7;
    const int sp = bid / 80;
    const int ti = TItab[tp], tj = TJtab[tp];
    const bool diag = (ti == tj);

    const int wave = t >> 6, lane = t & 63;
    const int lrow = lane & 15, q = lane >> 4;
    const int sr = t >> 2;            // 0..63
    const int sc = (t & 3) * 8;       // 0,8,16,24
    const float* gA = ff + ((size_t)(b * NC + ti * 64 + sr)) * DF + sp * KC + sc;
    const float* gB = ff + ((size_t)(b * NC + tj * 64 + sr)) * DF + sp * KC + sc;

    floatx4 a1[4], a2[4], a3[4];
    #pragma unroll
    for (int j = 0; j < 4; ++j) { a1[j] = (floatx4)0.f; a2[j] = (floatx4)0.f; a3[j] = (floatx4)0.f; }

    float4 ra0 = *(const float4*)(gA), ra1 = *(const float4*)(gA + 4);
    float4 rb0 = make_float4(0.f, 0.f, 0.f, 0.f), rb1 = rb0;
    if (!diag) { rb0 = *(const float4*)(gB); rb1 = *(const float4*)(gB + 4); }
    gA += BK; gB += BK;

    for (int it = 0; it < ITERS; ++it) {
      float fa[8] = {ra0.x, ra0.y, ra0.z, ra0.w, ra1.x, ra1.y, ra1.z, ra1.w};
      half8 ah, al;
      #pragma unroll
      for (int e = 0; e < 8; ++e) {
        _Float16 h = (_Float16)fa[e];
        ah[e] = h;
        al[e] = (_Float16)(fa[e] - (float)h);
      }
      half8 bh, bl;
      if (!diag) {
        float fb[8] = {rb0.x, rb0.y, rb0.z, rb0.w, rb1.x, rb1.y, rb1.z, rb1.w};
        #pragma unroll
        for (int e = 0; e < 8; ++e) {
          _Float16 h = (_Float16)fb[e];
          bh[e] = h;
          bl[e] = (_Float16)(fb[e] - (float)h);
        }
      }
      __syncthreads();
      *(half8*)&Ah[sr][sc] = ah;
      *(half8*)&Al[sr][sc] = al;
      if (!diag) {
        *(half8*)&Bh[sr][sc] = bh;
        *(half8*)&Bl[sr][sc] = bl;
      }
      __syncthreads();
      if (it + 1 < ITERS) {
        ra0 = *(const float4*)(gA); ra1 = *(const float4*)(gA + 4);
        if (!diag) { rb0 = *(const float4*)(gB); rb1 = *(const float4*)(gB + 4); }
        gA += BK; gB += BK;
      }
      const _Float16* bhp = diag ? &Ah[0][0] : &Bh[0][0];
      const _Float16* blp = diag ? &Al[0][0] : &Bl[0][0];
      half8 af = *(const half8*)&Ah[wave * 16 + lrow][q * 8];
      half8 lf = *(const half8*)&Al[wave * 16 + lrow][q * 8];
      #pragma unroll
      for (int j = 0; j < 4; ++j) {
        half8 bhf = *(const half8*)(bhp + (j * 16 + lrow) * 40 + q * 8);
        half8 blf = *(const half8*)(blp + (j * 16 + lrow) * 40 + q * 8);
        a1[j] = __builtin_amdgcn_mfma_f32_16x16x32_f16(af, bhf, a1[j], 0, 0, 0);
        a2[j] = __builtin_amdgcn_mfma_f32_16x16x32_f16(af, blf, a2[j], 0, 0, 0);
        a3[j] = __builtin_amdgcn_mfma_f32_16x16x32_f16(lf, bhf, a3[j], 0, 0, 0);
      }
    }

    float* Pb = Pp + (size_t)(sp * NB + b) * NC * NC;
    int grow = ti * 64 + wave * 16 + q * 4;
    #pragma unroll
    for (int j = 0; j < 4; ++j) {
      int gcol = tj * 64 + j * 16 + lrow;
      float4 v;
      v.x = a1[j][0] + a2[j][0] + a3[j][0];
      v.y = a1[j][1] + a2[j][1] + a3[j][1];
      v.z = a1[j][2] + a2[j][2] + a3[j][2];
      v.w = a1[j][3] + a2[j][3] + a3[j][3];
      Pb[(size_t)(grow + 0) * NC + gcol] = v.x;
      Pb[(size_t)(grow + 1) * NC + gcol] = v.y;
      Pb[(size_t)(grow + 2) * NC + gcol] = v.z;
      Pb[(size_t)(grow + 3) * NC + gcol] = v.w;
      if (!diag) *(float4*)&Pb[(size_t)gcol * NC + grow] = v;  // mirror
    }
    __threadfence();
    __syncthreads();
    if (t == 0) signal(&cnts[b]);   // gdone[b]
  }

  if (bid >= 256) return;

  // ================= formD phase (blocks 0..255, 8 rows each) ===================
  const int fb = bid >> 5, slot = bid & 31, i0 = slot * 8;
  if (t == 0) waitfor(&cnts[fb], 80);   // all gemm blocks of batch fb
  __syncthreads();
  __threadfence();
  {
    float s = 0.f;
    #pragma unroll
    for (int sp = 0; sp < SPLITS; ++sp)
      s += Pp[((size_t)(sp * NB + fb) * NC + t) * NC + t];
    dg_s[t] = s;
    __syncthreads();
    float colsum = 0.f;
    for (int ii = 0; ii < 8; ++ii) {
      int i = i0 + ii;
      float acc = 0.f;
      #pragma unroll
      for (int sp = 0; sp < SPLITS; ++sp)
        acc += Pp[((size_t)(sp * NB + fb) * NC + i) * NC + t];
      float d2 = dg_s[i] + dg_s[t] - 2.f * acc;
      float d = sqrtf(fmaxf(d2, 0.f));
      Db[((size_t)fb * NC + i) * NC + t] = d;
      colsum += d;
    }
    rsp[(size_t)(fb * 32 + slot) * NC + t] = colsum;  // per-block partial (no atomics)
  }
  __threadfence();
  __syncthreads();
  if (t == 0) signal(&cnts[8 + fb]);   // fcnt[fb]

  // ================= FPS phase (blocks 0,32,...,224) ============================
  if (slot == 0) {
    if (t == 0) waitfor(&cnts[8 + fb], 32);
    __syncthreads();
    __threadfence();
    const float* D = Db + (size_t)fb * NC * NC;
    float rst = 0.f;
    #pragma unroll
    for (int s = 0; s < 32; ++s) rst += rsp[(size_t)(fb * 32 + s) * NC + t];
    int start = argmax256(rst, sv, si);
    if (t == 0) fpsIdx[0] = start;
    float mind = D[start * NC + t];   // symmetric: row == col
    for (int it = 1; it < KCL; ++it) {
      int far = argmax256(mind, sv, si);
      if (t == 0) fpsIdx[it] = far;
      mind = fminf(mind, D[far * NC + t]);
    }
    __syncthreads();
    if (t < KCL) {
      int p = fpsIdx[t];
      ccoord[(fb * KCL + t) * 3 + 0] = pe[(fb * NC + p) * 3 + 0];
      ccoord[(fb * KCL + t) * 3 + 1] = pe[(fb * NC + p) * 3 + 1];
      ccoord[(fb * KCL + t) * 3 + 2] = pe[(fb * NC + p) * 3 + 2];
    }
    __threadfence();
    __syncthreads();
    if (t == 0) signal(&cnts[16]);   // fpsdone
  }

  // ================= final phase (block 0) ======================================
  if (bid == 0) {
    if (t == 0) { waitfor(&cnts[16], 8); waitfor(&cnts[17], 1); }
    __syncthreads();
    __threadfence();
    __shared__ float cc[NB * KCL * 3];
    __shared__ float cn[NB * KCL];
    __shared__ float sums[KCL][3];
    __shared__ int cnts_s[KCL];
    __shared__ float avg[KCL][3];
    __shared__ float an[KCL];
    __shared__ float c0[KCL * 3];
    __shared__ float c1x[KCL], c1y[KCL], c1z[KCL], c1n[KCL];
    __shared__ int order[NC][KCL];
    for (int i = t; i < NB * KCL * 3; i += 256) cc[i] = ccoord[i];
    if (t < KCL * 3) c0[t] = centers0[t];
    if (t < KCL) { sums[t][0] = 0.f; sums[t][1] = 0.f; sums[t][2] = 0.f; cnts_s[t] = 0; }
    __syncthreads();
    if (t < NB * KCL) {
      float x = cc[t * 3], y = cc[t * 3 + 1], z = cc[t * 3 + 2];
      cn[t] = x * x + y * y + z * z;
    }
    __syncthreads();
    for (int b = 0; b < NB; ++b) {
      int p = b * NC + t;
      float x = pe[p * 3], y = pe[p * 3 + 1], z = pe[p * 3 + 2];
      float n = x * x + y * y + z * z;
      float best = 3.4e38f; int bi = 0;
      #pragma unroll
      for (int k = 0; k < KCL; ++k) {
        int c = b * KCL + k;
        float dot = x * cc[c * 3] + y * cc[c * 3 + 1] + z * cc[c * 3 + 2];
        float d2 = fmaxf(n + cn[c] - 2.f * dot, 0.f);
        if (d2 < best) { best = d2; bi = k; }
      }
      atomicAdd(&sums[bi][0], x);
      atomicAdd(&sums[bi][1], y);
      atomicAdd(&sums[bi][2], z);
      atomicAdd(&cnts_s[bi], 1);
    }
    __syncthreads();
    if (t < KCL) {
      float c = (float)cnts_s[t];
      float inv = 1.f / fmaxf(c, 1.f);
      float ax = (cnts_s[t] > 0) ? sums[t][0] * inv : 0.f;
      float ay = (cnts_s[t] > 0) ? sums[t][1] * inv : 0.f;
      float az = (cnts_s[t] > 0) ? sums[t][2] * inv : 0.f;
      avg[t][0] = ax; avg[t][1] = ay; avg[t][2] = az;
      an[t] = ax * ax + ay * ay + az * az;
    }
    __syncthreads();
    if (t < KCL) {
      float x = c0[t * 3], y = c0[t * 3 + 1], z = c0[t * 3 + 2];
      float n = x * x + y * y + z * z;
      float best = 3.4e38f; int bi = 0;
      #pragma unroll
      for (int j = 0; j < KCL; ++j) {
        float dot = x * avg[j][0] + y * avg[j][1] + z * avg[j][2];
        float d2 = fmaxf(n + an[j] - 2.f * dot, 0.f);
        if (d2 < best) { best = d2; bi = j; }
      }
      float nx = 0.8f * x + 0.2f * avg[bi][0];
      float ny = 0.8f * y + 0.2f * avg[bi][1];
      float nz = 0.8f * z + 0.2f * avg[bi][2];
      c1x[t] = nx; c1y[t] = ny; c1z[t] = nz;
      c1n[t] = nx * nx + ny * ny + nz * nz;
    }
    __syncthreads();
    {
      float x = pe[t * 3], y = pe[t * 3 + 1], z = pe[t * 3 + 2];
      float n = x * x + y * y + z * z;
      float v[KCL];
      #pragma unroll
      for (int k = 0; k < KCL; ++k) {
        float dot = x * c1x[k] + y * c1y[k] + z * c1z[k];
        v[k] = fmaxf(n + c1n[k] - 2.f * dot, 0.f);
      }
      bool used[KCL];
      #pragma unroll
      for (int k = 0; k < KCL; ++k) used[k] = false;
      for (int r = 0; r < KCL; ++r) {
        float best = 3.4e38f; int bi = 0;
        #pragma unroll
        for (int j = 0; j < KCL; ++j) {
          if (!used[j] && v[j] < best) { best = v[j]; bi = j; }
        }
        order[t][r] = bi;
        used[bi] = true;
      }
    }
    __syncthreads();
    if (t < 64) {
      int cnt = 0;
      int cur = (t < KCL) ? order[0][t] : 0;
      for (int i = 0; i < NC; ++i) {
        int nxt = (t < KCL && i + 1 < NC) ? order[i + 1][t] : 0;
        int ccur = __shfl(cnt, cur);
        bool avail = (t < KCL) && (ccur < 16);
        unsigned long long m = __ballot(avail);
        int chosen;
        if (m != 0ull) {
          int rank = __ffsll((unsigned long long)m) - 1;
          chosen = __shfl(cur, rank);
        } else {
          chosen = __shfl(cur, 0);
        }
        if (t == chosen) cnt++;
        if (t == 0) outp[i] = chosen;
        cur = nxt;
      }
    }
  }
}

extern "C" void kernel_launch(void* const* d_in, const int* in_sizes, int n_in,
                              void* d_out, int out_size, void* d_ws, size_t ws_size,
                              hipStream_t stream) {
  (void)in_sizes; (void)n_in; (void)out_size; (void)ws_size;
  const float* features = (const float*)d_in[0];
  const float* pe = (const float*)d_in[1];
  char* ws = (char*)d_ws;
  float* Pp       = (float*)(ws);                  // 8*8*256*256*4 = 16 MiB
  float* Db       = (float*)(ws + 16777216);       // 2 MiB
  float* rsp      = (float*)(ws + 18874368);       // 8*32*256*4 = 256 KiB
  float* centers0 = (float*)(ws + 19136512);       // 192 B (padded to 512)
  float* ccoord   = (float*)(ws + 19137024);       // 1.5 KiB
  int*   cnts     = (int*)  (ws + 19138560);       // 18 ints
  int*   outp     = (int*)d_out;

  hipMemsetAsync(cnts, 0, 128, stream);
  hipLaunchKernelGGL(k_fused, dim3(GEMM_BLOCKS + 1), dim3(256), 0, stream,
                     features, pe, Pp, Db, rsp, centers0, ccoord, cnts, outp);
}